// Round 12
// baseline (1042.540 us; speedup 1.0000x reference)
//
#include <hip/hip_runtime.h>

#define CIN 64
#define COUT 128
#define NC 64        // conv stat buckets
#define NSB 32       // skip stat buckets
#define LDT 132      // padded LDS row stride (dwords)
#define SKB 256      // skip role blocks

typedef __bf16 bf16x8 __attribute__((ext_vector_type(8)));
typedef __bf16 bf16x4 __attribute__((ext_vector_type(4)));
typedef float  f32x4  __attribute__((ext_vector_type(4)));

// ---------------------------------------------------------------------------
// Fused prep: role-dispatch on blockIdx.x.
// ---------------------------------------------------------------------------
__global__ __launch_bounds__(256) void prep_kernel(
    const float* __restrict__ feats, __bf16* __restrict__ fb,
    const float* __restrict__ Wc, const float* __restrict__ Ws, __bf16* __restrict__ wf,
    const int* __restrict__ cin_idx, const int* __restrict__ cout_idx, int* __restrict__ tap_in,
    const int* __restrict__ sout, int* __restrict__ inv,
    const int* __restrict__ boo, int* __restrict__ msplit,
    int total8, int P, int cpb, int Ls, int N, int M,
    int nbA, int nbAB, int nbABC, int nbABCD)
{
    const int bid = blockIdx.x, t = threadIdx.x;
    if (bid < nbA) {                                  // A: feats -> bf16
        const int i = bid * 256 + t;
        if (i >= total8) return;
        const int i8 = i * 8;
        const float4 x0 = *(const float4*)(feats + i8);
        const float4 x1 = *(const float4*)(feats + i8 + 4);
        bf16x8 v;
        v[0] = (__bf16)x0.x; v[1] = (__bf16)x0.y; v[2] = (__bf16)x0.z; v[3] = (__bf16)x0.w;
        v[4] = (__bf16)x1.x; v[5] = (__bf16)x1.y; v[6] = (__bf16)x1.z; v[7] = (__bf16)x1.w;
        *(bf16x8*)(fb + i8) = v;
    } else if (bid < nbAB) {                          // B: wfrag pack
        const int id = (bid - nbA) * 256 + t;
        if (id >= 160 * 64) return;
        const int f = id >> 6, lane = id & 63;
        const float* W; int r;
        if (f < 144) { W = Wc + (size_t)(f >> 4) * CIN * COUT; r = f & 15; }
        else         { W = Ws;                                  r = f - 144; }
        const int c = r >> 1, s = r & 1;
        const int kbase = s * 32 + (lane >> 4) * 8;
        const int col = c * 16 + (lane & 15);
        bf16x8 v;
#pragma unroll
        for (int j = 0; j < 8; ++j) v[j] = (__bf16)W[(size_t)(kbase + j) * COUT + col];
        *(bf16x8*)(wf + ((size_t)f * 64 + lane) * 8) = v;
    } else if (bid < nbABC) {                         // C: tap scatter
        const int c = bid - nbAB;
        const int k = c / cpb;
        const int e = (c - k * cpb) * 256 + t;
        if (e >= P) return;
        const int oo = cout_idx[(size_t)k * P + e];
        if (oo < M) tap_in[(size_t)k * M + oo] = cin_idx[(size_t)k * P + e];
    } else if (bid < nbABCD) {                        // D: inverse skip map
        const int i = (bid - nbABC) * 256 + t;
        if (i < Ls) inv[sout[i]] = i;
    } else {                                          // tail: zero row + msplit
        if (t < 64) fb[(size_t)N * CIN + t] = (__bf16)0.f;
        if (t == 0) {
            int lo = 0, hi = M;
            while (lo < hi) { const int mid = (lo + hi) >> 1; if (boo[mid] < 1) lo = mid + 1; else hi = mid; }
            msplit[0] = lo;
        }
    }
}

// ---------------------------------------------------------------------------
// Pattern extraction + histogram (counting sort pass 1).
// ---------------------------------------------------------------------------
__global__ __launch_bounds__(256) void pat_kernel(
    const int* __restrict__ tap_in, int* __restrict__ pat_arr,
    int* __restrict__ hist, int M, int N)
{
    __shared__ int lh[512];
    const int t = threadIdx.x;
    lh[t] = 0; lh[t + 256] = 0;
    __syncthreads();
    const int m = blockIdx.x * 256 + t;
    if (m < M) {
        int p = 0;
#pragma unroll
        for (int k = 0; k < 9; ++k)
            p |= (tap_in[(size_t)k * M + m] < N) << k;
        pat_arr[m] = p;
        atomicAdd(&lh[p], 1);
    }
    __syncthreads();
    for (int i = t; i < 512; i += 256)
        if (lh[i]) atomicAdd(&hist[i], lh[i]);
}

// ---------------------------------------------------------------------------
// Scan: pad counts to x16, exclusive scan -> cursor; ngroups.
// ---------------------------------------------------------------------------
__global__ __launch_bounds__(512) void scan_kernel(
    const int* __restrict__ hist, int* __restrict__ cursor, int* __restrict__ ng_dev)
{
    __shared__ int buf[512];
    const int p = threadIdx.x;
    const int pc = (hist[p] + 15) & ~15;
    buf[p] = pc;
    __syncthreads();
    for (int off = 1; off < 512; off <<= 1) {
        const int v = (p >= off) ? buf[p - off] : 0;
        __syncthreads();
        buf[p] += v;
        __syncthreads();
    }
    cursor[p] = buf[p] - pc;              // exclusive
    if (p == 511) ng_dev[0] = buf[511] >> 4;
}

// ---------------------------------------------------------------------------
// Scatter rows into pattern-sorted order.
// ---------------------------------------------------------------------------
__global__ __launch_bounds__(256) void scatter_kernel(
    const int* __restrict__ pat_arr, int* __restrict__ cursor,
    int* __restrict__ rowid, int* __restrict__ spat, int* __restrict__ boob,
    const int* __restrict__ boo, int M)
{
    const int m = blockIdx.x * 256 + threadIdx.x;
    if (m >= M) return;
    const int p = pat_arr[m];
    const int pos = atomicAdd(&cursor[p], 1);
    rowid[pos] = m;
    spat[pos] = p;
    boob[pos] = boo[m];
}

// ---------------------------------------------------------------------------
// Fused conv + skip. Conv: one wave per 16-row pattern-sorted group; only
// valid taps processed (avg 1.66/9). D[8] in regs; per-wave LDS transpose;
// raw bf16 row store in sorted order; bucketed stats.
// ---------------------------------------------------------------------------
__global__ __launch_bounds__(256, 4) void conv_mfma_kernel(
    const __bf16* __restrict__ fb,      // [N+1][CIN], row N zeros
    const __bf16* __restrict__ wf,
    const int* __restrict__ tap_in,     // [9][M]
    const int* __restrict__ rowid,      // [maxS]
    const int* __restrict__ spat,
    const int* __restrict__ boob,
    const int* __restrict__ ng_dev,
    const int* __restrict__ sin_idx,
    __bf16* __restrict__ raw,           // [maxS][128] sorted raw conv output
    float* __restrict__ G,
    float* __restrict__ zstats,         // [NC*384 conv | NSB*256 skip]
    int N, int M, int Ls)
{
    __shared__ float tile[4 * 16 * LDT];   // 33.8 KB
    __shared__ float wred[3][4][128];      // 6 KB (skip role reuses [0..1][0][...])
    const int t = threadIdx.x, lane = t & 63, wv = t >> 6;
    const int arow = lane & 15, apart = lane >> 4;

    if (blockIdx.x < SKB) {
        // ---------------- skip role ----------------
        const __bf16* wk = wf + ((size_t)144 * 64 + lane) * 8;
        const bf16x8 b00 = *(const bf16x8*)(wk + (size_t)(wv * 4 + 0) * 512);
        const bf16x8 b01 = *(const bf16x8*)(wk + (size_t)(wv * 4 + 1) * 512);
        const bf16x8 b10 = *(const bf16x8*)(wk + (size_t)(wv * 4 + 2) * 512);
        const bf16x8 b11 = *(const bf16x8*)(wk + (size_t)(wv * 4 + 3) * 512);
        const int colA = wv * 32 + arow;
        const int colB = colA + 16;

        float s1A = 0.f, s2A = 0.f, s1B = 0.f, s2B = 0.f;
        const int ngroups = (Ls + 15) >> 4;
        for (int g = blockIdx.x; g < ngroups; g += SKB) {
            const int e0 = g * 16;
            const int ea = e0 + arow;
            const int ii = (ea < Ls) ? sin_idx[ea] : 0;
            const __bf16* fr = fb + (size_t)ii * CIN + apart * 8;
            const bf16x8 a0 = *(const bf16x8*)fr;
            const bf16x8 a1 = *(const bf16x8*)(fr + 32);

            f32x4 dA = {0.f,0.f,0.f,0.f};
            f32x4 dB = {0.f,0.f,0.f,0.f};
            dA = __builtin_amdgcn_mfma_f32_16x16x32_bf16(a0, b00, dA, 0, 0, 0);
            dA = __builtin_amdgcn_mfma_f32_16x16x32_bf16(a1, b01, dA, 0, 0, 0);
            dB = __builtin_amdgcn_mfma_f32_16x16x32_bf16(a0, b10, dB, 0, 0, 0);
            dB = __builtin_amdgcn_mfma_f32_16x16x32_bf16(a1, b11, dB, 0, 0, 0);

            const int er = e0 + apart * 4;
#pragma unroll
            for (int j = 0; j < 4; ++j) {
                if (er + j < Ls) {
                    const float vA = dA[j], vB = dB[j];
                    G[(size_t)(er + j) * COUT + colA] = vA;
                    G[(size_t)(er + j) * COUT + colB] = vB;
                    s1A += vA; s2A += vA * vA;
                    s1B += vB; s2B += vB * vB;
                }
            }
        }
        s1A += __shfl_xor(s1A, 16); s1A += __shfl_xor(s1A, 32);
        s2A += __shfl_xor(s2A, 16); s2A += __shfl_xor(s2A, 32);
        s1B += __shfl_xor(s1B, 16); s1B += __shfl_xor(s1B, 32);
        s2B += __shfl_xor(s2B, 16); s2B += __shfl_xor(s2B, 32);
        if (apart == 0) {
            wred[0][0][colA] = s1A; wred[0][0][colB] = s1B;
            wred[1][0][colA] = s2A; wred[1][0][colB] = s2B;
        }
        __syncthreads();
        float* bucket = zstats + NC * 384 + (size_t)(blockIdx.x & (NSB - 1)) * 256;
        if (t < 128) {
            atomicAdd(&bucket[t],       wred[0][0][t]);
            atomicAdd(&bucket[128 + t], wred[1][0][t]);
        }
        return;
    }

    // ---------------- conv role: one wave = one 16-row sorted group ----------------
    const int ng = ng_dev[0];
    const int g = (blockIdx.x - SKB) * 4 + wv;
    const bool live = g < ng;
    const int m0 = g * 16;

    f32x4 D[8];
#pragma unroll
    for (int c = 0; c < 8; ++c) D[c] = (f32x4){0.f,0.f,0.f,0.f};

    int rid = -1, pattern = 0;
    if (live) {
        rid = rowid[m0 + arow];
        pattern = spat[m0];                // uniform across wave by construction
    }

    for (int pk = pattern; pk; pk &= (pk - 1)) {
        const int k = __builtin_ctz(pk);
        const int vi = (rid >= 0) ? tap_in[(size_t)k * M + rid] : N;
        const __bf16* f0 = fb + (size_t)vi * CIN + apart * 8;
        const bf16x8 a0 = *(const bf16x8*)f0;
        const bf16x8 a1 = *(const bf16x8*)(f0 + 32);
        const __bf16* wb = wf + ((size_t)(k * 16) * 64 + lane) * 8;
#pragma unroll
        for (int c = 0; c < 8; ++c) {
            const bf16x8 b0 = *(const bf16x8*)(wb + (size_t)(c * 2 + 0) * 512);
            const bf16x8 b1 = *(const bf16x8*)(wb + (size_t)(c * 2 + 1) * 512);
            D[c] = __builtin_amdgcn_mfma_f32_16x16x32_bf16(a0, b0, D[c], 0, 0, 0);
            D[c] = __builtin_amdgcn_mfma_f32_16x16x32_bf16(a1, b1, D[c], 0, 0, 0);
        }
    }

    // stats (padding rows have exact-0 values -> harmless)
    float ssum[8], sq[8], s0[8];
#pragma unroll
    for (int c = 0; c < 8; ++c) { ssum[c] = 0.f; sq[c] = 0.f; s0[c] = 0.f; }
    int4 bb = {1, 1, 1, 1};
    if (live) bb = *(const int4*)&boob[m0 + apart * 4];
#pragma unroll
    for (int c = 0; c < 8; ++c) {
        const float v0 = D[c][0], v1 = D[c][1], v2 = D[c][2], v3 = D[c][3];
        ssum[c] += v0 + v1 + v2 + v3;
        sq[c]   += v0*v0 + v1*v1 + v2*v2 + v3*v3;
        if (bb.x == 0) s0[c] += v0;
        if (bb.y == 0) s0[c] += v1;
        if (bb.z == 0) s0[c] += v2;
        if (bb.w == 0) s0[c] += v3;
    }

    // per-wave LDS transpose -> coalesced bf16 raw store (sorted order)
    float* T = tile + wv * (16 * LDT);
#pragma unroll
    for (int c = 0; c < 8; ++c)
#pragma unroll
        for (int j = 0; j < 4; ++j)
            T[(apart * 4 + j) * LDT + c * 16 + arow] = D[c][j];
    if (live) {
#pragma unroll
        for (int i = 0; i < 8; ++i) {
            const int r = i * 2 + (lane >> 5);
            const int c4 = (lane & 31) * 4;
            const f32x4 vv = *(const f32x4*)&T[r * LDT + c4];
            bf16x4 o;
            o[0] = (__bf16)vv[0]; o[1] = (__bf16)vv[1];
            o[2] = (__bf16)vv[2]; o[3] = (__bf16)vv[3];
            *(bf16x4*)&raw[(size_t)(m0 + r) * 128 + c4] = o;
        }
    }

    // reduce stats: shuffle over apart -> per-wave slot -> bucket atomics
#pragma unroll
    for (int c = 0; c < 8; ++c) {
        ssum[c] += __shfl_xor(ssum[c], 16); ssum[c] += __shfl_xor(ssum[c], 32);
        s0[c]   += __shfl_xor(s0[c], 16);   s0[c]   += __shfl_xor(s0[c], 32);
        sq[c]   += __shfl_xor(sq[c], 16);   sq[c]   += __shfl_xor(sq[c], 32);
    }
    if (apart == 0) {
#pragma unroll
        for (int c = 0; c < 8; ++c) {
            const int col = c * 16 + arow;
            wred[0][wv][col] = s0[c];
            wred[1][wv][col] = ssum[c] - s0[c];
            wred[2][wv][col] = sq[c];
        }
    }
    __syncthreads();
    float* bucket = zstats + (size_t)(blockIdx.x & (NC - 1)) * 384;
    if (t < 128) {
        atomicAdd(&bucket[t],       wred[0][0][t] + wred[0][1][t] + wred[0][2][t] + wred[0][3][t]);
        atomicAdd(&bucket[128 + t], wred[1][0][t] + wred[1][1][t] + wred[1][2][t] + wred[1][3][t]);
        atomicAdd(&bucket[256 + t], wred[2][0][t] + wred[2][1][t] + wred[2][2][t] + wred[2][3][t]);
    }
}

// ---------------------------------------------------------------------------
// Single-block: reduce buckets, BN params (main + skip), SE MLP.
// ---------------------------------------------------------------------------
__global__ __launch_bounds__(128) void params_kernel(
    const float* __restrict__ zstats,
    const int* __restrict__ msplit_p,
    const float* __restrict__ gamma, const float* __restrict__ beta,
    const float* __restrict__ sgamma, const float* __restrict__ sbeta,
    const float* __restrict__ fc1, const float* __restrict__ fc2,
    float* __restrict__ scale, float* __restrict__ shift,
    float* __restrict__ sscale, float* __restrict__ sshift,
    float* __restrict__ attn,
    int Ls, int M)
{
    __shared__ float desc[2][COUT];
    __shared__ float hid[2][8];
    const int ch = threadIdx.x;

    float s0 = 0.f, s1 = 0.f, q = 0.f;
    for (int b = 0; b < NC; ++b) {
        const float* st = zstats + (size_t)b * 384;
        s0 += st[ch]; s1 += st[128 + ch]; q += st[256 + ch];
    }
    float ss = 0.f, sqk = 0.f;
    const float* sk = zstats + NC * 384;
    for (int b = 0; b < NSB; ++b) {
        ss  += sk[(size_t)b * 256 + ch];
        sqk += sk[(size_t)b * 256 + 128 + ch];
    }

    const float c0 = (float)msplit_p[0], c1 = (float)M - c0;
    const float Mf = (float)M;
    const float mu  = (s0 + s1) / Mf;
    const float var = q / Mf - mu * mu;
    const float rs  = rsqrtf(var + 1e-5f);
    const float sc  = rs * gamma[ch];
    const float sh  = beta[ch] - mu * sc;
    scale[ch] = sc;
    shift[ch] = sh;
    desc[0][ch] = (s0 / c0) * sc + sh;
    desc[1][ch] = (s1 / c1) * sc + sh;

    const float lsf  = (float)Ls;
    const float mus  = ss / lsf;
    const float vars = sqk / lsf - mus * mus;
    const float rss  = rsqrtf(vars + 1e-5f);
    const float ssc  = rss * sgamma[ch];
    sscale[ch] = ssc;
    sshift[ch] = sbeta[ch] - mus * ssc;

    __syncthreads();
    if (ch < 16) {
        const int b = ch >> 3, h = ch & 7;
        float a = 0.f;
        for (int c = 0; c < COUT; ++c) a += desc[b][c] * fc1[c * 8 + h];
        hid[b][h] = fmaxf(a, 0.f);
    }
    __syncthreads();
    for (int b = 0; b < 2; ++b) {
        float a = 0.f;
        for (int h = 0; h < 8; ++h) a += hid[b][h] * fc2[h * COUT + ch];
        attn[b * COUT + ch] = 1.f / (1.f + expf(-a));
    }
}

// ---------------------------------------------------------------------------
// Epilogue: for sorted row s -> orig rid: out[rid] = relu(bn(raw)*attn + skip).
// ---------------------------------------------------------------------------
__global__ __launch_bounds__(256) void final_kernel(
    const __bf16* __restrict__ raw,
    const int* __restrict__ rowid,
    const int* __restrict__ boob,
    float* __restrict__ out,
    const float* __restrict__ G,
    const int* __restrict__ inv_skip,
    const float* __restrict__ scale, const float* __restrict__ shift,
    const float* __restrict__ sscale, const float* __restrict__ sshift,
    const float* __restrict__ attn,
    int Smax)
{
    const int t  = threadIdx.x;
    const int c4 = (t & 31) * 4;
    const int rw = t >> 5;
    const float4 sc  = *(const float4*)&scale[c4];
    const float4 sh  = *(const float4*)&shift[c4];
    const float4 ssc = *(const float4*)&sscale[c4];
    const float4 ssh = *(const float4*)&sshift[c4];
    const float4 at0 = *(const float4*)&attn[c4];
    const float4 at1 = *(const float4*)&attn[COUT + c4];

    for (int s = blockIdx.x * 8 + rw; s < Smax; s += gridDim.x * 8) {
        const int rid = rowid[s];
        if (rid < 0) continue;
        const bf16x4 rv = *(const bf16x4*)&raw[(size_t)s * COUT + c4];
        const int b = boob[s];
        const int j = inv_skip[rid];
        const float4 av = b ? at1 : at0;
        float4 y;
        y.x = ((float)rv[0] * sc.x + sh.x) * av.x;
        y.y = ((float)rv[1] * sc.y + sh.y) * av.y;
        y.z = ((float)rv[2] * sc.z + sh.z) * av.z;
        y.w = ((float)rv[3] * sc.w + sh.w) * av.w;
        if (j >= 0) {
            const float4 gg = *(const float4*)&G[(size_t)j * COUT + c4];
            y.x += gg.x * ssc.x + ssh.x;
            y.y += gg.y * ssc.y + ssh.y;
            y.z += gg.z * ssc.z + ssh.z;
            y.w += gg.w * ssc.w + ssh.w;
        }
        y.x = y.x > 0.f ? y.x : 0.f;
        y.y = y.y > 0.f ? y.y : 0.f;
        y.z = y.z > 0.f ? y.z : 0.f;
        y.w = y.w > 0.f ? y.w : 0.f;
        *(float4*)&out[(size_t)rid * COUT + c4] = y;
    }
}

extern "C" void kernel_launch(void* const* d_in, const int* in_sizes, int n_in,
                              void* d_out, int out_size, void* d_ws, size_t ws_size,
                              hipStream_t stream)
{
    const float* feats  = (const float*)d_in[0];
    const float* Wc     = (const float*)d_in[1];
    const float* Wsk    = (const float*)d_in[2];
    const float* gamma  = (const float*)d_in[3];
    const float* beta   = (const float*)d_in[4];
    const float* sgamma = (const float*)d_in[5];
    const float* sbeta  = (const float*)d_in[6];
    const float* fc1    = (const float*)d_in[7];
    const float* fc2    = (const float*)d_in[8];
    const int* cin_idx  = (const int*)d_in[9];
    const int* cout_idx = (const int*)d_in[10];
    const int* sin_idx  = (const int*)d_in[11];
    const int* sout_idx = (const int*)d_in[12];
    const int* boo      = (const int*)d_in[13];

    const int N  = in_sizes[0] / CIN;
    const int P  = in_sizes[9] / 9;
    const int Ls = in_sizes[11];
    const int M  = in_sizes[13];
    const int maxS = ((M + 15) & ~15) + 512 * 16;   // upper bound on sorted rows
    const int maxG = maxS >> 4;

    float* out = (float*)d_out;

    // workspace layout
    char* ws = (char*)d_ws;
    __bf16* fb = (__bf16*)ws;                       // (N+1) x CIN
    size_t off = (size_t)(N + 1) * CIN * sizeof(__bf16);
    off = (off + 255) & ~(size_t)255;
    __bf16* wfrag = (__bf16*)(ws + off);
    off += (size_t)160 * 64 * 8 * sizeof(__bf16);
    off = (off + 255) & ~(size_t)255;
    int* tap_in = (int*)(ws + off);                 // 9 x M
    off += (size_t)9 * M * sizeof(int);
    off = (off + 255) & ~(size_t)255;
    float* G = (float*)(ws + off);                  // Ls x COUT
    off += (size_t)Ls * COUT * sizeof(float);
    int* inv_skip = (int*)(ws + off);               // M
    off += (size_t)M * sizeof(int);
    off = (off + 255) & ~(size_t)255;
    int* pat_arr = (int*)(ws + off);                // M
    off += (size_t)M * sizeof(int);
    off = (off + 255) & ~(size_t)255;
    int* rowid = (int*)(ws + off);                  // maxS
    off += (size_t)maxS * sizeof(int);
    int* spat = (int*)(ws + off);                   // maxS
    off += (size_t)maxS * sizeof(int);
    int* boob = (int*)(ws + off);                   // maxS
    off += (size_t)maxS * sizeof(int);
    off = (off + 255) & ~(size_t)255;
    __bf16* raw = (__bf16*)(ws + off);              // maxS x 128 bf16
    off += (size_t)maxS * COUT * sizeof(__bf16);
    off = (off + 255) & ~(size_t)255;
    int* hist = (int*)(ws + off);                   // 512
    off += 512 * sizeof(int);
    int* cursor = (int*)(ws + off);                 // 512
    off += 512 * sizeof(int);
    int* ng_dev = (int*)(ws + off);
    off += 256;
    float* zstats = (float*)(ws + off);             // NC*384 + NSB*256
    off += (size_t)(NC * 384 + NSB * 256) * sizeof(float);
    int* msplit = (int*)(ws + off);
    off += 256;
    float* params = (float*)(ws + off);
    float* scale = params, *shift = params + 128;
    float* sscale = params + 256, *sshift = params + 384, *attn = params + 512;

    hipMemsetAsync(zstats, 0, (size_t)(NC * 384 + NSB * 256) * sizeof(float), stream);
    hipMemsetAsync(inv_skip, 0xFF, (size_t)M * sizeof(int), stream);      // -1
    hipMemsetAsync(tap_in, 0x7F, (size_t)9 * M * sizeof(int), stream);    // big sentinel
    hipMemsetAsync(hist, 0, 512 * sizeof(int), stream);
    hipMemsetAsync(rowid, 0xFF, (size_t)maxS * sizeof(int), stream);      // -1
    hipMemsetAsync(boob, 0, (size_t)maxS * sizeof(int), stream);

    // fused prep
    const int total8 = N * CIN / 8;
    const int nbA = (total8 + 255) / 256;
    const int nbB = (160 * 64 + 255) / 256;
    const int cpb = (P + 255) / 256;
    const int nbAB = nbA + nbB;
    const int nbABC = nbAB + 9 * cpb;
    const int nbABCD = nbABC + (Ls + 255) / 256;
    prep_kernel<<<nbABCD + 1, 256, 0, stream>>>(
        feats, fb, Wc, Wsk, wfrag, cin_idx, cout_idx, tap_in, sout_idx, inv_skip,
        boo, msplit, total8, P, cpb, Ls, N, M, nbA, nbAB, nbABC, nbABCD);

    // pattern sort
    pat_kernel<<<(M + 255) / 256, 256, 0, stream>>>(tap_in, pat_arr, hist, M, N);
    scan_kernel<<<1, 512, 0, stream>>>(hist, cursor, ng_dev);
    scatter_kernel<<<(M + 255) / 256, 256, 0, stream>>>(pat_arr, cursor, rowid, spat, boob, boo, M);

    conv_mfma_kernel<<<SKB + (maxG + 3) / 4, 256, 0, stream>>>(
        fb, wfrag, tap_in, rowid, spat, boob, ng_dev, sin_idx,
        raw, G, zstats, N, M, Ls);

    params_kernel<<<1, 128, 0, stream>>>(
        zstats, msplit, gamma, beta, sgamma, sbeta, fc1, fc2,
        scale, shift, sscale, sshift, attn, Ls, M);

    final_kernel<<<2048, 256, 0, stream>>>(
        raw, rowid, boob, out, G, inv_skip,
        scale, shift, sscale, sshift, attn, maxS);
}

// Round 13
// 218.098 us; speedup vs baseline: 4.7802x; 4.7802x over previous
//
#include <hip/hip_runtime.h>

#define CIN 64
#define COUT 128
#define NC 64        // conv stat buckets
#define NSB 32       // skip stat buckets
#define LDT 132      // padded LDS row stride (dwords)
#define SKB 256      // skip role blocks
#define SB 256       // sort blocks

typedef __bf16 bf16x8 __attribute__((ext_vector_type(8)));
typedef __bf16 bf16x4 __attribute__((ext_vector_type(4)));
typedef float  f32x4  __attribute__((ext_vector_type(4)));

// ---------------------------------------------------------------------------
// Fused prep: role-dispatch on blockIdx.x.
// ---------------------------------------------------------------------------
__global__ __launch_bounds__(256) void prep_kernel(
    const float* __restrict__ feats, __bf16* __restrict__ fb,
    const float* __restrict__ Wc, const float* __restrict__ Ws, __bf16* __restrict__ wf,
    const int* __restrict__ cin_idx, const int* __restrict__ cout_idx, int* __restrict__ tap_in,
    const int* __restrict__ sout, int* __restrict__ inv,
    const int* __restrict__ boo, int* __restrict__ msplit,
    int total8, int P, int cpb, int Ls, int N, int M,
    int nbA, int nbAB, int nbABC, int nbABCD)
{
    const int bid = blockIdx.x, t = threadIdx.x;
    if (bid < nbA) {                                  // A: feats -> bf16
        const int i = bid * 256 + t;
        if (i >= total8) return;
        const int i8 = i * 8;
        const float4 x0 = *(const float4*)(feats + i8);
        const float4 x1 = *(const float4*)(feats + i8 + 4);
        bf16x8 v;
        v[0] = (__bf16)x0.x; v[1] = (__bf16)x0.y; v[2] = (__bf16)x0.z; v[3] = (__bf16)x0.w;
        v[4] = (__bf16)x1.x; v[5] = (__bf16)x1.y; v[6] = (__bf16)x1.z; v[7] = (__bf16)x1.w;
        *(bf16x8*)(fb + i8) = v;
    } else if (bid < nbAB) {                          // B: wfrag pack
        const int id = (bid - nbA) * 256 + t;
        if (id >= 160 * 64) return;
        const int f = id >> 6, lane = id & 63;
        const float* W; int r;
        if (f < 144) { W = Wc + (size_t)(f >> 4) * CIN * COUT; r = f & 15; }
        else         { W = Ws;                                  r = f - 144; }
        const int c = r >> 1, s = r & 1;
        const int kbase = s * 32 + (lane >> 4) * 8;
        const int col = c * 16 + (lane & 15);
        bf16x8 v;
#pragma unroll
        for (int j = 0; j < 8; ++j) v[j] = (__bf16)W[(size_t)(kbase + j) * COUT + col];
        *(bf16x8*)(wf + ((size_t)f * 64 + lane) * 8) = v;
    } else if (bid < nbABC) {                         // C: tap scatter
        const int c = bid - nbAB;
        const int k = c / cpb;
        const int e = (c - k * cpb) * 256 + t;
        if (e >= P) return;
        const int oo = cout_idx[(size_t)k * P + e];
        if (oo < M) tap_in[(size_t)k * M + oo] = cin_idx[(size_t)k * P + e];
    } else if (bid < nbABCD) {                        // D: inverse skip map
        const int i = (bid - nbABC) * 256 + t;
        if (i < Ls) inv[sout[i]] = i;
    } else {                                          // tail: zero row + msplit
        if (t < 64) fb[(size_t)N * CIN + t] = (__bf16)0.f;
        if (t == 0) {
            int lo = 0, hi = M;
            while (lo < hi) { const int mid = (lo + hi) >> 1; if (boo[mid] < 1) lo = mid + 1; else hi = mid; }
            msplit[0] = lo;
        }
    }
}

// ---------------------------------------------------------------------------
// Sort pass 1: pattern extraction + per-block histogram (no global atomics).
// Block bid owns rows [bid*rpb, (bid+1)*rpb).
// ---------------------------------------------------------------------------
__global__ __launch_bounds__(256) void pat_kernel(
    const int* __restrict__ tap_in, int* __restrict__ pat_arr,
    int* __restrict__ bh, int M, int N, int rpb)
{
    __shared__ int lh[512];
    const int t = threadIdx.x, bid = blockIdx.x;
    lh[t] = 0; lh[t + 256] = 0;
    __syncthreads();
    const int mend = min((bid + 1) * rpb, M);
    for (int m = bid * rpb + t; m < mend; m += 256) {
        int p = 0;
#pragma unroll
        for (int k = 0; k < 9; ++k)
            p |= (tap_in[(size_t)k * M + m] < N) << k;
        pat_arr[m] = p;
        atomicAdd(&lh[p], 1);             // LDS atomic
    }
    __syncthreads();
    bh[bid * 512 + t]       = lh[t];
    bh[bid * 512 + t + 256] = lh[t + 256];
}

// ---------------------------------------------------------------------------
// Sort pass 2 (1 block): column totals, padded-x16 exclusive scan over
// patterns, then rewrite bh[b][p] as per-block base offsets. No atomics.
// ---------------------------------------------------------------------------
__global__ __launch_bounds__(512) void scan_kernel(
    int* __restrict__ bh, int* __restrict__ ng_dev)
{
    __shared__ int buf[512];
    const int p = threadIdx.x;
    int total = 0;
    for (int b = 0; b < SB; ++b) total += bh[b * 512 + p];
    const int pc = (total + 15) & ~15;
    buf[p] = pc;
    __syncthreads();
    for (int off = 1; off < 512; off <<= 1) {
        const int v = (p >= off) ? buf[p - off] : 0;
        __syncthreads();
        buf[p] += v;
        __syncthreads();
    }
    int running = buf[p] - pc;            // exclusive bin start (x16 aligned)
    if (p == 511) ng_dev[0] = buf[511] >> 4;
    for (int b = 0; b < SB; ++b) {
        const int c = bh[b * 512 + p];
        bh[b * 512 + p] = running;
        running += c;
    }
}

// ---------------------------------------------------------------------------
// Sort pass 3: scatter rows using per-block bases + LDS-atomic local ranks.
// ---------------------------------------------------------------------------
__global__ __launch_bounds__(256) void scatter_kernel(
    const int* __restrict__ pat_arr, const int* __restrict__ bh,
    int* __restrict__ rowid, int* __restrict__ spat, int* __restrict__ boob,
    const int* __restrict__ boo, int M, int rpb)
{
    __shared__ int lcur[512];
    const int t = threadIdx.x, bid = blockIdx.x;
    lcur[t]       = bh[bid * 512 + t];
    lcur[t + 256] = bh[bid * 512 + t + 256];
    __syncthreads();
    const int mend = min((bid + 1) * rpb, M);
    for (int m = bid * rpb + t; m < mend; m += 256) {
        const int p = pat_arr[m];
        const int pos = atomicAdd(&lcur[p], 1);   // LDS atomic
        rowid[pos] = m;
        spat[pos] = p;
        boob[pos] = boo[m];
    }
}

// ---------------------------------------------------------------------------
// Fused conv + skip. Conv: one wave per 16-row pattern-sorted group; only
// valid taps processed (avg ~1.2/9). D[8] in regs; per-wave LDS transpose;
// raw bf16 row store in sorted order; bucketed stats.
// ---------------------------------------------------------------------------
__global__ __launch_bounds__(256, 4) void conv_mfma_kernel(
    const __bf16* __restrict__ fb,      // [N+1][CIN], row N zeros
    const __bf16* __restrict__ wf,
    const int* __restrict__ tap_in,     // [9][M]
    const int* __restrict__ rowid,      // [maxS]
    const int* __restrict__ spat,
    const int* __restrict__ boob,
    const int* __restrict__ ng_dev,
    const int* __restrict__ sin_idx,
    __bf16* __restrict__ raw,           // [maxS][128] sorted raw conv output
    float* __restrict__ G,
    float* __restrict__ zstats,         // [NC*384 conv | NSB*256 skip]
    int N, int M, int Ls)
{
    __shared__ float tile[4 * 16 * LDT];   // 33.8 KB
    __shared__ float wred[3][4][128];      // 6 KB
    const int t = threadIdx.x, lane = t & 63, wv = t >> 6;
    const int arow = lane & 15, apart = lane >> 4;

    if (blockIdx.x < SKB) {
        // ---------------- skip role ----------------
        const __bf16* wk = wf + ((size_t)144 * 64 + lane) * 8;
        const bf16x8 b00 = *(const bf16x8*)(wk + (size_t)(wv * 4 + 0) * 512);
        const bf16x8 b01 = *(const bf16x8*)(wk + (size_t)(wv * 4 + 1) * 512);
        const bf16x8 b10 = *(const bf16x8*)(wk + (size_t)(wv * 4 + 2) * 512);
        const bf16x8 b11 = *(const bf16x8*)(wk + (size_t)(wv * 4 + 3) * 512);
        const int colA = wv * 32 + arow;
        const int colB = colA + 16;

        float s1A = 0.f, s2A = 0.f, s1B = 0.f, s2B = 0.f;
        const int ngroups = (Ls + 15) >> 4;
        for (int g = blockIdx.x; g < ngroups; g += SKB) {
            const int e0 = g * 16;
            const int ea = e0 + arow;
            const int ii = (ea < Ls) ? sin_idx[ea] : 0;
            const __bf16* fr = fb + (size_t)ii * CIN + apart * 8;
            const bf16x8 a0 = *(const bf16x8*)fr;
            const bf16x8 a1 = *(const bf16x8*)(fr + 32);

            f32x4 dA = {0.f,0.f,0.f,0.f};
            f32x4 dB = {0.f,0.f,0.f,0.f};
            dA = __builtin_amdgcn_mfma_f32_16x16x32_bf16(a0, b00, dA, 0, 0, 0);
            dA = __builtin_amdgcn_mfma_f32_16x16x32_bf16(a1, b01, dA, 0, 0, 0);
            dB = __builtin_amdgcn_mfma_f32_16x16x32_bf16(a0, b10, dB, 0, 0, 0);
            dB = __builtin_amdgcn_mfma_f32_16x16x32_bf16(a1, b11, dB, 0, 0, 0);

            const int er = e0 + apart * 4;
#pragma unroll
            for (int j = 0; j < 4; ++j) {
                if (er + j < Ls) {
                    const float vA = dA[j], vB = dB[j];
                    G[(size_t)(er + j) * COUT + colA] = vA;
                    G[(size_t)(er + j) * COUT + colB] = vB;
                    s1A += vA; s2A += vA * vA;
                    s1B += vB; s2B += vB * vB;
                }
            }
        }
        s1A += __shfl_xor(s1A, 16); s1A += __shfl_xor(s1A, 32);
        s2A += __shfl_xor(s2A, 16); s2A += __shfl_xor(s2A, 32);
        s1B += __shfl_xor(s1B, 16); s1B += __shfl_xor(s1B, 32);
        s2B += __shfl_xor(s2B, 16); s2B += __shfl_xor(s2B, 32);
        if (apart == 0) {
            wred[0][0][colA] = s1A; wred[0][0][colB] = s1B;
            wred[1][0][colA] = s2A; wred[1][0][colB] = s2B;
        }
        __syncthreads();
        float* bucket = zstats + NC * 384 + (size_t)(blockIdx.x & (NSB - 1)) * 256;
        if (t < 128) {
            atomicAdd(&bucket[t],       wred[0][0][t]);
            atomicAdd(&bucket[128 + t], wred[1][0][t]);
        }
        return;
    }

    // ---------------- conv role: one wave = one 16-row sorted group ----------------
    const int ng = ng_dev[0];
    const int g = (blockIdx.x - SKB) * 4 + wv;
    const bool live = g < ng;
    const int m0 = g * 16;

    f32x4 D[8];
#pragma unroll
    for (int c = 0; c < 8; ++c) D[c] = (f32x4){0.f,0.f,0.f,0.f};

    int rid = -1, pattern = 0;
    if (live) {
        rid = rowid[m0 + arow];
        pattern = spat[m0];                // uniform across wave by construction
    }

    for (int pk = pattern; pk; pk &= (pk - 1)) {
        const int k = __builtin_ctz(pk);
        const int vi = (rid >= 0) ? tap_in[(size_t)k * M + rid] : N;
        const __bf16* f0 = fb + (size_t)vi * CIN + apart * 8;
        const bf16x8 a0 = *(const bf16x8*)f0;
        const bf16x8 a1 = *(const bf16x8*)(f0 + 32);
        const __bf16* wb = wf + ((size_t)(k * 16) * 64 + lane) * 8;
#pragma unroll
        for (int c = 0; c < 8; ++c) {
            const bf16x8 b0 = *(const bf16x8*)(wb + (size_t)(c * 2 + 0) * 512);
            const bf16x8 b1 = *(const bf16x8*)(wb + (size_t)(c * 2 + 1) * 512);
            D[c] = __builtin_amdgcn_mfma_f32_16x16x32_bf16(a0, b0, D[c], 0, 0, 0);
            D[c] = __builtin_amdgcn_mfma_f32_16x16x32_bf16(a1, b1, D[c], 0, 0, 0);
        }
    }

    // stats (padding rows are exact 0 -> harmless)
    float ssum[8], sq[8], s0[8];
#pragma unroll
    for (int c = 0; c < 8; ++c) { ssum[c] = 0.f; sq[c] = 0.f; s0[c] = 0.f; }
    int4 bb = {1, 1, 1, 1};
    if (live) bb = *(const int4*)&boob[m0 + apart * 4];
#pragma unroll
    for (int c = 0; c < 8; ++c) {
        const float v0 = D[c][0], v1 = D[c][1], v2 = D[c][2], v3 = D[c][3];
        ssum[c] += v0 + v1 + v2 + v3;
        sq[c]   += v0*v0 + v1*v1 + v2*v2 + v3*v3;
        if (bb.x == 0) s0[c] += v0;
        if (bb.y == 0) s0[c] += v1;
        if (bb.z == 0) s0[c] += v2;
        if (bb.w == 0) s0[c] += v3;
    }

    // per-wave LDS transpose -> coalesced bf16 raw store (sorted order)
    float* T = tile + wv * (16 * LDT);
#pragma unroll
    for (int c = 0; c < 8; ++c)
#pragma unroll
        for (int j = 0; j < 4; ++j)
            T[(apart * 4 + j) * LDT + c * 16 + arow] = D[c][j];
    if (live) {
#pragma unroll
        for (int i = 0; i < 8; ++i) {
            const int r = i * 2 + (lane >> 5);
            const int c4 = (lane & 31) * 4;
            const f32x4 vv = *(const f32x4*)&T[r * LDT + c4];
            bf16x4 o;
            o[0] = (__bf16)vv[0]; o[1] = (__bf16)vv[1];
            o[2] = (__bf16)vv[2]; o[3] = (__bf16)vv[3];
            *(bf16x4*)&raw[(size_t)(m0 + r) * 128 + c4] = o;
        }
    }

    // reduce stats: shuffle over apart -> per-wave slot -> bucket atomics
#pragma unroll
    for (int c = 0; c < 8; ++c) {
        ssum[c] += __shfl_xor(ssum[c], 16); ssum[c] += __shfl_xor(ssum[c], 32);
        s0[c]   += __shfl_xor(s0[c], 16);   s0[c]   += __shfl_xor(s0[c], 32);
        sq[c]   += __shfl_xor(sq[c], 16);   sq[c]   += __shfl_xor(sq[c], 32);
    }
    if (apart == 0) {
#pragma unroll
        for (int c = 0; c < 8; ++c) {
            const int col = c * 16 + arow;
            wred[0][wv][col] = s0[c];
            wred[1][wv][col] = ssum[c] - s0[c];
            wred[2][wv][col] = sq[c];
        }
    }
    __syncthreads();
    float* bucket = zstats + (size_t)(blockIdx.x & (NC - 1)) * 384;
    if (t < 128) {
        atomicAdd(&bucket[t],       wred[0][0][t] + wred[0][1][t] + wred[0][2][t] + wred[0][3][t]);
        atomicAdd(&bucket[128 + t], wred[1][0][t] + wred[1][1][t] + wred[1][2][t] + wred[1][3][t]);
        atomicAdd(&bucket[256 + t], wred[2][0][t] + wred[2][1][t] + wred[2][2][t] + wred[2][3][t]);
    }
}

// ---------------------------------------------------------------------------
// Single-block: reduce buckets, BN params (main + skip), SE MLP.
// ---------------------------------------------------------------------------
__global__ __launch_bounds__(128) void params_kernel(
    const float* __restrict__ zstats,
    const int* __restrict__ msplit_p,
    const float* __restrict__ gamma, const float* __restrict__ beta,
    const float* __restrict__ sgamma, const float* __restrict__ sbeta,
    const float* __restrict__ fc1, const float* __restrict__ fc2,
    float* __restrict__ scale, float* __restrict__ shift,
    float* __restrict__ sscale, float* __restrict__ sshift,
    float* __restrict__ attn,
    int Ls, int M)
{
    __shared__ float desc[2][COUT];
    __shared__ float hid[2][8];
    const int ch = threadIdx.x;

    float s0 = 0.f, s1 = 0.f, q = 0.f;
    for (int b = 0; b < NC; ++b) {
        const float* st = zstats + (size_t)b * 384;
        s0 += st[ch]; s1 += st[128 + ch]; q += st[256 + ch];
    }
    float ss = 0.f, sqk = 0.f;
    const float* sk = zstats + NC * 384;
    for (int b = 0; b < NSB; ++b) {
        ss  += sk[(size_t)b * 256 + ch];
        sqk += sk[(size_t)b * 256 + 128 + ch];
    }

    const float c0 = (float)msplit_p[0], c1 = (float)M - c0;
    const float Mf = (float)M;
    const float mu  = (s0 + s1) / Mf;
    const float var = q / Mf - mu * mu;
    const float rs  = rsqrtf(var + 1e-5f);
    const float sc  = rs * gamma[ch];
    const float sh  = beta[ch] - mu * sc;
    scale[ch] = sc;
    shift[ch] = sh;
    desc[0][ch] = (s0 / c0) * sc + sh;
    desc[1][ch] = (s1 / c1) * sc + sh;

    const float lsf  = (float)Ls;
    const float mus  = ss / lsf;
    const float vars = sqk / lsf - mus * mus;
    const float rss  = rsqrtf(vars + 1e-5f);
    const float ssc  = rss * sgamma[ch];
    sscale[ch] = ssc;
    sshift[ch] = sbeta[ch] - mus * ssc;

    __syncthreads();
    if (ch < 16) {
        const int b = ch >> 3, h = ch & 7;
        float a = 0.f;
        for (int c = 0; c < COUT; ++c) a += desc[b][c] * fc1[c * 8 + h];
        hid[b][h] = fmaxf(a, 0.f);
    }
    __syncthreads();
    for (int b = 0; b < 2; ++b) {
        float a = 0.f;
        for (int h = 0; h < 8; ++h) a += hid[b][h] * fc2[h * COUT + ch];
        attn[b * COUT + ch] = 1.f / (1.f + expf(-a));
    }
}

// ---------------------------------------------------------------------------
// Epilogue: for sorted row s -> orig rid: out[rid] = relu(bn(raw)*attn + skip).
// ---------------------------------------------------------------------------
__global__ __launch_bounds__(256) void final_kernel(
    const __bf16* __restrict__ raw,
    const int* __restrict__ rowid,
    const int* __restrict__ boob,
    float* __restrict__ out,
    const float* __restrict__ G,
    const int* __restrict__ inv_skip,
    const float* __restrict__ scale, const float* __restrict__ shift,
    const float* __restrict__ sscale, const float* __restrict__ sshift,
    const float* __restrict__ attn,
    int Smax)
{
    const int t  = threadIdx.x;
    const int c4 = (t & 31) * 4;
    const int rw = t >> 5;
    const float4 sc  = *(const float4*)&scale[c4];
    const float4 sh  = *(const float4*)&shift[c4];
    const float4 ssc = *(const float4*)&sscale[c4];
    const float4 ssh = *(const float4*)&sshift[c4];
    const float4 at0 = *(const float4*)&attn[c4];
    const float4 at1 = *(const float4*)&attn[COUT + c4];

    for (int s = blockIdx.x * 8 + rw; s < Smax; s += gridDim.x * 8) {
        const int rid = rowid[s];
        if (rid < 0) continue;
        const bf16x4 rv = *(const bf16x4*)&raw[(size_t)s * COUT + c4];
        const int b = boob[s];
        const int j = inv_skip[rid];
        const float4 av = b ? at1 : at0;
        float4 y;
        y.x = ((float)rv[0] * sc.x + sh.x) * av.x;
        y.y = ((float)rv[1] * sc.y + sh.y) * av.y;
        y.z = ((float)rv[2] * sc.z + sh.z) * av.z;
        y.w = ((float)rv[3] * sc.w + sh.w) * av.w;
        if (j >= 0) {
            const float4 gg = *(const float4*)&G[(size_t)j * COUT + c4];
            y.x += gg.x * ssc.x + ssh.x;
            y.y += gg.y * ssc.y + ssh.y;
            y.z += gg.z * ssc.z + ssh.z;
            y.w += gg.w * ssc.w + ssh.w;
        }
        y.x = y.x > 0.f ? y.x : 0.f;
        y.y = y.y > 0.f ? y.y : 0.f;
        y.z = y.z > 0.f ? y.z : 0.f;
        y.w = y.w > 0.f ? y.w : 0.f;
        *(float4*)&out[(size_t)rid * COUT + c4] = y;
    }
}

extern "C" void kernel_launch(void* const* d_in, const int* in_sizes, int n_in,
                              void* d_out, int out_size, void* d_ws, size_t ws_size,
                              hipStream_t stream)
{
    const float* feats  = (const float*)d_in[0];
    const float* Wc     = (const float*)d_in[1];
    const float* Wsk    = (const float*)d_in[2];
    const float* gamma  = (const float*)d_in[3];
    const float* beta   = (const float*)d_in[4];
    const float* sgamma = (const float*)d_in[5];
    const float* sbeta  = (const float*)d_in[6];
    const float* fc1    = (const float*)d_in[7];
    const float* fc2    = (const float*)d_in[8];
    const int* cin_idx  = (const int*)d_in[9];
    const int* cout_idx = (const int*)d_in[10];
    const int* sin_idx  = (const int*)d_in[11];
    const int* sout_idx = (const int*)d_in[12];
    const int* boo      = (const int*)d_in[13];

    const int N  = in_sizes[0] / CIN;
    const int P  = in_sizes[9] / 9;
    const int Ls = in_sizes[11];
    const int M  = in_sizes[13];
    const int maxS = ((M + 15) & ~15) + 512 * 16;   // upper bound on sorted rows
    const int maxG = maxS >> 4;
    const int rpb = (M + SB - 1) / SB;              // rows per sort block

    float* out = (float*)d_out;

    // workspace layout
    char* ws = (char*)d_ws;
    __bf16* fb = (__bf16*)ws;                       // (N+1) x CIN
    size_t off = (size_t)(N + 1) * CIN * sizeof(__bf16);
    off = (off + 255) & ~(size_t)255;
    __bf16* wfrag = (__bf16*)(ws + off);
    off += (size_t)160 * 64 * 8 * sizeof(__bf16);
    off = (off + 255) & ~(size_t)255;
    int* tap_in = (int*)(ws + off);                 // 9 x M
    off += (size_t)9 * M * sizeof(int);
    off = (off + 255) & ~(size_t)255;
    float* G = (float*)(ws + off);                  // Ls x COUT
    off += (size_t)Ls * COUT * sizeof(float);
    int* inv_skip = (int*)(ws + off);               // M
    off += (size_t)M * sizeof(int);
    off = (off + 255) & ~(size_t)255;
    int* pat_arr = (int*)(ws + off);                // M
    off += (size_t)M * sizeof(int);
    off = (off + 255) & ~(size_t)255;
    int* rowid = (int*)(ws + off);                  // maxS
    off += (size_t)maxS * sizeof(int);
    int* spat = (int*)(ws + off);                   // maxS
    off += (size_t)maxS * sizeof(int);
    int* boob = (int*)(ws + off);                   // maxS
    off += (size_t)maxS * sizeof(int);
    off = (off + 255) & ~(size_t)255;
    __bf16* raw = (__bf16*)(ws + off);              // maxS x 128 bf16
    off += (size_t)maxS * COUT * sizeof(__bf16);
    off = (off + 255) & ~(size_t)255;
    int* bh = (int*)(ws + off);                     // SB x 512 block hists/bases
    off += (size_t)SB * 512 * sizeof(int);
    int* ng_dev = (int*)(ws + off);
    off += 256;
    float* zstats = (float*)(ws + off);             // NC*384 + NSB*256
    off += (size_t)(NC * 384 + NSB * 256) * sizeof(float);
    int* msplit = (int*)(ws + off);
    off += 256;
    float* params = (float*)(ws + off);
    float* scale = params, *shift = params + 128;
    float* sscale = params + 256, *sshift = params + 384, *attn = params + 512;

    hipMemsetAsync(zstats, 0, (size_t)(NC * 384 + NSB * 256) * sizeof(float), stream);
    hipMemsetAsync(inv_skip, 0xFF, (size_t)M * sizeof(int), stream);      // -1
    hipMemsetAsync(tap_in, 0x7F, (size_t)9 * M * sizeof(int), stream);    // big sentinel
    hipMemsetAsync(rowid, 0xFF, (size_t)maxS * sizeof(int), stream);      // -1
    hipMemsetAsync(boob, 0, (size_t)maxS * sizeof(int), stream);

    // fused prep
    const int total8 = N * CIN / 8;
    const int nbA = (total8 + 255) / 256;
    const int nbB = (160 * 64 + 255) / 256;
    const int cpb = (P + 255) / 256;
    const int nbAB = nbA + nbB;
    const int nbABC = nbAB + 9 * cpb;
    const int nbABCD = nbABC + (Ls + 255) / 256;
    prep_kernel<<<nbABCD + 1, 256, 0, stream>>>(
        feats, fb, Wc, Wsk, wfrag, cin_idx, cout_idx, tap_in, sout_idx, inv_skip,
        boo, msplit, total8, P, cpb, Ls, N, M, nbA, nbAB, nbABC, nbABCD);

    // pattern sort (atomic-free, two-level)
    pat_kernel<<<SB, 256, 0, stream>>>(tap_in, pat_arr, bh, M, N, rpb);
    scan_kernel<<<1, 512, 0, stream>>>(bh, ng_dev);
    scatter_kernel<<<SB, 256, 0, stream>>>(pat_arr, bh, rowid, spat, boob, boo, M, rpb);

    conv_mfma_kernel<<<SKB + (maxG + 3) / 4, 256, 0, stream>>>(
        fb, wfrag, tap_in, rowid, spat, boob, ng_dev, sin_idx,
        raw, G, zstats, N, M, Ls);

    params_kernel<<<1, 128, 0, stream>>>(
        zstats, msplit, gamma, beta, sgamma, sbeta, fc1, fc2,
        scale, shift, sscale, sshift, attn, Ls, M);

    final_kernel<<<2048, 256, 0, stream>>>(
        raw, rowid, boob, out, G, inv_skip,
        scale, shift, sscale, sshift, attn, maxS);
}

// Round 14
// 212.208 us; speedup vs baseline: 4.9128x; 1.0278x over previous
//
#include <hip/hip_runtime.h>

#define CIN 64
#define COUT 128
#define NC 64        // conv stat buckets
#define NSB 32       // skip stat buckets
#define LDT 132      // padded LDS row stride (dwords)
#define SKB 256      // skip role blocks
#define SB 256       // sort blocks

typedef __bf16 bf16x8 __attribute__((ext_vector_type(8)));
typedef __bf16 bf16x4 __attribute__((ext_vector_type(4)));
typedef float  f32x4  __attribute__((ext_vector_type(4)));

// ---------------------------------------------------------------------------
// Fused prep: role-dispatch on blockIdx.x.  Role C also builds the per-row
// tap-validity bitmask via atomicOr (371k distinct words -> no contention).
// ---------------------------------------------------------------------------
__global__ __launch_bounds__(256) void prep_kernel(
    const float* __restrict__ feats, __bf16* __restrict__ fb,
    const float* __restrict__ Wc, const float* __restrict__ Ws, __bf16* __restrict__ wf,
    const int* __restrict__ cin_idx, const int* __restrict__ cout_idx, int* __restrict__ tap_in,
    int* __restrict__ pat_arr,
    const int* __restrict__ sout, int* __restrict__ inv,
    const int* __restrict__ boo, int* __restrict__ msplit,
    int total8, int P, int cpb, int Ls, int N, int M,
    int nbA, int nbAB, int nbABC, int nbABCD)
{
    const int bid = blockIdx.x, t = threadIdx.x;
    if (bid < nbA) {                                  // A: feats -> bf16
        const int i = bid * 256 + t;
        if (i >= total8) return;
        const int i8 = i * 8;
        const float4 x0 = *(const float4*)(feats + i8);
        const float4 x1 = *(const float4*)(feats + i8 + 4);
        bf16x8 v;
        v[0] = (__bf16)x0.x; v[1] = (__bf16)x0.y; v[2] = (__bf16)x0.z; v[3] = (__bf16)x0.w;
        v[4] = (__bf16)x1.x; v[5] = (__bf16)x1.y; v[6] = (__bf16)x1.z; v[7] = (__bf16)x1.w;
        *(bf16x8*)(fb + i8) = v;
    } else if (bid < nbAB) {                          // B: wfrag pack
        const int id = (bid - nbA) * 256 + t;
        if (id >= 160 * 64) return;
        const int f = id >> 6, lane = id & 63;
        const float* W; int r;
        if (f < 144) { W = Wc + (size_t)(f >> 4) * CIN * COUT; r = f & 15; }
        else         { W = Ws;                                  r = f - 144; }
        const int c = r >> 1, s = r & 1;
        const int kbase = s * 32 + (lane >> 4) * 8;
        const int col = c * 16 + (lane & 15);
        bf16x8 v;
#pragma unroll
        for (int j = 0; j < 8; ++j) v[j] = (__bf16)W[(size_t)(kbase + j) * COUT + col];
        *(bf16x8*)(wf + ((size_t)f * 64 + lane) * 8) = v;
    } else if (bid < nbABC) {                         // C: tap scatter + bitmask
        const int c = bid - nbAB;
        const int k = c / cpb;
        const int e = (c - k * cpb) * 256 + t;
        if (e >= P) return;
        const int oo = cout_idx[(size_t)k * P + e];
        if (oo < M) {
            tap_in[(size_t)k * M + oo] = cin_idx[(size_t)k * P + e];
            atomicOr(&pat_arr[oo], 1 << k);
        }
    } else if (bid < nbABCD) {                        // D: inverse skip map
        const int i = (bid - nbABC) * 256 + t;
        if (i < Ls) inv[sout[i]] = i;
    } else {                                          // tail: zero row + msplit
        if (t < 64) fb[(size_t)N * CIN + t] = (__bf16)0.f;
        if (t == 0) {
            int lo = 0, hi = M;
            while (lo < hi) { const int mid = (lo + hi) >> 1; if (boo[mid] < 1) lo = mid + 1; else hi = mid; }
            msplit[0] = lo;
        }
    }
}

// ---------------------------------------------------------------------------
// Sort pass 1: per-block histogram from pat_arr (no global atomics).
// ---------------------------------------------------------------------------
__global__ __launch_bounds__(256) void pat_kernel(
    const int* __restrict__ pat_arr, int* __restrict__ bh, int M, int rpb)
{
    __shared__ int lh[512];
    const int t = threadIdx.x, bid = blockIdx.x;
    lh[t] = 0; lh[t + 256] = 0;
    __syncthreads();
    const int mend = min((bid + 1) * rpb, M);
    for (int m = bid * rpb + t; m < mend; m += 256)
        atomicAdd(&lh[pat_arr[m]], 1);    // LDS atomic
    __syncthreads();
    bh[bid * 512 + t]       = lh[t];
    bh[bid * 512 + t + 256] = lh[t + 256];
}

// ---------------------------------------------------------------------------
// Sort pass 2 (1 block): column totals, padded-x16 exclusive scan over
// patterns, rewrite bh[b][p] as per-block bases, fill rowid pad slots (-1).
// ---------------------------------------------------------------------------
__global__ __launch_bounds__(512) void scan_kernel(
    int* __restrict__ bh, int* __restrict__ rowid, int* __restrict__ ng_dev)
{
    __shared__ int buf[512];
    const int p = threadIdx.x;
    int total = 0;
    for (int b = 0; b < SB; ++b) total += bh[b * 512 + p];
    const int pc = (total + 15) & ~15;
    buf[p] = pc;
    __syncthreads();
    for (int off = 1; off < 512; off <<= 1) {
        const int v = (p >= off) ? buf[p - off] : 0;
        __syncthreads();
        buf[p] += v;
        __syncthreads();
    }
    int running = buf[p] - pc;            // exclusive bin start (x16 aligned)
    if (p == 511) ng_dev[0] = buf[511] >> 4;
    for (int b = 0; b < SB; ++b) {
        const int c = bh[b * 512 + p];
        bh[b * 512 + p] = running;
        running += c;
    }
    // pad slots [start+total, start+pc) -> rowid = -1
    for (int x = running; x < buf[p]; ++x) rowid[x] = -1;
}

// ---------------------------------------------------------------------------
// Sort pass 3: scatter rows using per-block bases + LDS-atomic local ranks.
// ---------------------------------------------------------------------------
__global__ __launch_bounds__(256) void scatter_kernel(
    const int* __restrict__ pat_arr, const int* __restrict__ bh,
    int* __restrict__ rowid, int* __restrict__ spat, int* __restrict__ boob,
    const int* __restrict__ boo, int M, int rpb)
{
    __shared__ int lcur[512];
    const int t = threadIdx.x, bid = blockIdx.x;
    lcur[t]       = bh[bid * 512 + t];
    lcur[t + 256] = bh[bid * 512 + t + 256];
    __syncthreads();
    const int mend = min((bid + 1) * rpb, M);
    for (int m = bid * rpb + t; m < mend; m += 256) {
        const int p = pat_arr[m];
        const int pos = atomicAdd(&lcur[p], 1);   // LDS atomic
        rowid[pos] = m;
        spat[pos] = p;
        boob[pos] = boo[m];
    }
}

// ---------------------------------------------------------------------------
// Fused conv + skip. Conv: one wave per 16-row pattern-sorted group; only
// valid taps processed. D[8] in regs; per-wave LDS transpose; raw bf16 row
// store in sorted order; bucketed stats. Skip: gather-GEMM -> bf16 G.
// ---------------------------------------------------------------------------
__global__ __launch_bounds__(256, 4) void conv_mfma_kernel(
    const __bf16* __restrict__ fb,      // [N+1][CIN], row N zeros
    const __bf16* __restrict__ wf,
    const int* __restrict__ tap_in,     // [9][M] (valid entries only)
    const int* __restrict__ rowid,      // [maxS]
    const int* __restrict__ spat,
    const int* __restrict__ boob,
    const int* __restrict__ ng_dev,
    const int* __restrict__ sin_idx,
    __bf16* __restrict__ raw,           // [maxS][128] sorted raw conv output
    __bf16* __restrict__ G,             // [Ls][128] bf16
    float* __restrict__ zstats,         // [NC*384 conv | NSB*256 skip]
    int N, int M, int Ls)
{
    __shared__ float tile[4 * 16 * LDT];   // 33.8 KB
    __shared__ float wred[3][4][128];      // 6 KB
    const int t = threadIdx.x, lane = t & 63, wv = t >> 6;
    const int arow = lane & 15, apart = lane >> 4;

    if (blockIdx.x < SKB) {
        // ---------------- skip role ----------------
        const __bf16* wk = wf + ((size_t)144 * 64 + lane) * 8;
        const bf16x8 b00 = *(const bf16x8*)(wk + (size_t)(wv * 4 + 0) * 512);
        const bf16x8 b01 = *(const bf16x8*)(wk + (size_t)(wv * 4 + 1) * 512);
        const bf16x8 b10 = *(const bf16x8*)(wk + (size_t)(wv * 4 + 2) * 512);
        const bf16x8 b11 = *(const bf16x8*)(wk + (size_t)(wv * 4 + 3) * 512);
        const int colA = wv * 32 + arow;
        const int colB = colA + 16;

        float s1A = 0.f, s2A = 0.f, s1B = 0.f, s2B = 0.f;
        const int ngroups = (Ls + 15) >> 4;
        for (int g = blockIdx.x; g < ngroups; g += SKB) {
            const int e0 = g * 16;
            const int ea = e0 + arow;
            const int ii = (ea < Ls) ? sin_idx[ea] : 0;
            const __bf16* fr = fb + (size_t)ii * CIN + apart * 8;
            const bf16x8 a0 = *(const bf16x8*)fr;
            const bf16x8 a1 = *(const bf16x8*)(fr + 32);

            f32x4 dA = {0.f,0.f,0.f,0.f};
            f32x4 dB = {0.f,0.f,0.f,0.f};
            dA = __builtin_amdgcn_mfma_f32_16x16x32_bf16(a0, b00, dA, 0, 0, 0);
            dA = __builtin_amdgcn_mfma_f32_16x16x32_bf16(a1, b01, dA, 0, 0, 0);
            dB = __builtin_amdgcn_mfma_f32_16x16x32_bf16(a0, b10, dB, 0, 0, 0);
            dB = __builtin_amdgcn_mfma_f32_16x16x32_bf16(a1, b11, dB, 0, 0, 0);

            const int er = e0 + apart * 4;
#pragma unroll
            for (int j = 0; j < 4; ++j) {
                if (er + j < Ls) {
                    const float vA = dA[j], vB = dB[j];
                    G[(size_t)(er + j) * COUT + colA] = (__bf16)vA;
                    G[(size_t)(er + j) * COUT + colB] = (__bf16)vB;
                    s1A += vA; s2A += vA * vA;
                    s1B += vB; s2B += vB * vB;
                }
            }
        }
        s1A += __shfl_xor(s1A, 16); s1A += __shfl_xor(s1A, 32);
        s2A += __shfl_xor(s2A, 16); s2A += __shfl_xor(s2A, 32);
        s1B += __shfl_xor(s1B, 16); s1B += __shfl_xor(s1B, 32);
        s2B += __shfl_xor(s2B, 16); s2B += __shfl_xor(s2B, 32);
        if (apart == 0) {
            wred[0][0][colA] = s1A; wred[0][0][colB] = s1B;
            wred[1][0][colA] = s2A; wred[1][0][colB] = s2B;
        }
        __syncthreads();
        float* bucket = zstats + NC * 384 + (size_t)(blockIdx.x & (NSB - 1)) * 256;
        if (t < 128) {
            atomicAdd(&bucket[t],       wred[0][0][t]);
            atomicAdd(&bucket[128 + t], wred[1][0][t]);
        }
        return;
    }

    // ---------------- conv role: one wave = one 16-row sorted group ----------------
    const int ng = ng_dev[0];
    const int g = (blockIdx.x - SKB) * 4 + wv;
    const bool live = g < ng;
    const int m0 = g * 16;

    f32x4 D[8];
#pragma unroll
    for (int c = 0; c < 8; ++c) D[c] = (f32x4){0.f,0.f,0.f,0.f};

    int rid = -1, pattern = 0;
    if (live) {
        rid = rowid[m0 + arow];
        pattern = spat[m0];                // uniform across wave by construction
    }

    for (int pk = pattern; pk; pk &= (pk - 1)) {
        const int k = __builtin_ctz(pk);
        const int vi = (rid >= 0) ? tap_in[(size_t)k * M + rid] : N;
        const __bf16* f0 = fb + (size_t)vi * CIN + apart * 8;
        const bf16x8 a0 = *(const bf16x8*)f0;
        const bf16x8 a1 = *(const bf16x8*)(f0 + 32);
        const __bf16* wb = wf + ((size_t)(k * 16) * 64 + lane) * 8;
#pragma unroll
        for (int c = 0; c < 8; ++c) {
            const bf16x8 b0 = *(const bf16x8*)(wb + (size_t)(c * 2 + 0) * 512);
            const bf16x8 b1 = *(const bf16x8*)(wb + (size_t)(c * 2 + 1) * 512);
            D[c] = __builtin_amdgcn_mfma_f32_16x16x32_bf16(a0, b0, D[c], 0, 0, 0);
            D[c] = __builtin_amdgcn_mfma_f32_16x16x32_bf16(a1, b1, D[c], 0, 0, 0);
        }
    }

    // stats (padding rows are exact 0 -> harmless; boob garbage on pads gates 0-adds)
    float ssum[8], sq[8], s0[8];
#pragma unroll
    for (int c = 0; c < 8; ++c) { ssum[c] = 0.f; sq[c] = 0.f; s0[c] = 0.f; }
    int4 bb = {1, 1, 1, 1};
    if (live) bb = *(const int4*)&boob[m0 + apart * 4];
#pragma unroll
    for (int c = 0; c < 8; ++c) {
        const float v0 = D[c][0], v1 = D[c][1], v2 = D[c][2], v3 = D[c][3];
        ssum[c] += v0 + v1 + v2 + v3;
        sq[c]   += v0*v0 + v1*v1 + v2*v2 + v3*v3;
        if (bb.x == 0) s0[c] += v0;
        if (bb.y == 0) s0[c] += v1;
        if (bb.z == 0) s0[c] += v2;
        if (bb.w == 0) s0[c] += v3;
    }

    // per-wave LDS transpose -> coalesced bf16 raw store (sorted order)
    float* T = tile + wv * (16 * LDT);
#pragma unroll
    for (int c = 0; c < 8; ++c)
#pragma unroll
        for (int j = 0; j < 4; ++j)
            T[(apart * 4 + j) * LDT + c * 16 + arow] = D[c][j];
    if (live) {
#pragma unroll
        for (int i = 0; i < 8; ++i) {
            const int r = i * 2 + (lane >> 5);
            const int c4 = (lane & 31) * 4;
            const f32x4 vv = *(const f32x4*)&T[r * LDT + c4];
            bf16x4 o;
            o[0] = (__bf16)vv[0]; o[1] = (__bf16)vv[1];
            o[2] = (__bf16)vv[2]; o[3] = (__bf16)vv[3];
            *(bf16x4*)&raw[(size_t)(m0 + r) * 128 + c4] = o;
        }
    }

    // reduce stats: shuffle over apart -> per-wave slot -> bucket atomics
#pragma unroll
    for (int c = 0; c < 8; ++c) {
        ssum[c] += __shfl_xor(ssum[c], 16); ssum[c] += __shfl_xor(ssum[c], 32);
        s0[c]   += __shfl_xor(s0[c], 16);   s0[c]   += __shfl_xor(s0[c], 32);
        sq[c]   += __shfl_xor(sq[c], 16);   sq[c]   += __shfl_xor(sq[c], 32);
    }
    if (apart == 0) {
#pragma unroll
        for (int c = 0; c < 8; ++c) {
            const int col = c * 16 + arow;
            wred[0][wv][col] = s0[c];
            wred[1][wv][col] = ssum[c] - s0[c];
            wred[2][wv][col] = sq[c];
        }
    }
    __syncthreads();
    float* bucket = zstats + (size_t)(blockIdx.x & (NC - 1)) * 384;
    if (t < 128) {
        atomicAdd(&bucket[t],       wred[0][0][t] + wred[0][1][t] + wred[0][2][t] + wred[0][3][t]);
        atomicAdd(&bucket[128 + t], wred[1][0][t] + wred[1][1][t] + wred[1][2][t] + wred[1][3][t]);
        atomicAdd(&bucket[256 + t], wred[2][0][t] + wred[2][1][t] + wred[2][2][t] + wred[2][3][t]);
    }
}

// ---------------------------------------------------------------------------
// Single-block: reduce buckets, BN params (main + skip), SE MLP.
// ---------------------------------------------------------------------------
__global__ __launch_bounds__(128) void params_kernel(
    const float* __restrict__ zstats,
    const int* __restrict__ msplit_p,
    const float* __restrict__ gamma, const float* __restrict__ beta,
    const float* __restrict__ sgamma, const float* __restrict__ sbeta,
    const float* __restrict__ fc1, const float* __restrict__ fc2,
    float* __restrict__ scale, float* __restrict__ shift,
    float* __restrict__ sscale, float* __restrict__ sshift,
    float* __restrict__ attn,
    int Ls, int M)
{
    __shared__ float desc[2][COUT];
    __shared__ float hid[2][8];
    const int ch = threadIdx.x;

    float s0 = 0.f, s1 = 0.f, q = 0.f;
    for (int b = 0; b < NC; ++b) {
        const float* st = zstats + (size_t)b * 384;
        s0 += st[ch]; s1 += st[128 + ch]; q += st[256 + ch];
    }
    float ss = 0.f, sqk = 0.f;
    const float* sk = zstats + NC * 384;
    for (int b = 0; b < NSB; ++b) {
        ss  += sk[(size_t)b * 256 + ch];
        sqk += sk[(size_t)b * 256 + 128 + ch];
    }

    const float c0 = (float)msplit_p[0], c1 = (float)M - c0;
    const float Mf = (float)M;
    const float mu  = (s0 + s1) / Mf;
    const float var = q / Mf - mu * mu;
    const float rs  = rsqrtf(var + 1e-5f);
    const float sc  = rs * gamma[ch];
    const float sh  = beta[ch] - mu * sc;
    scale[ch] = sc;
    shift[ch] = sh;
    desc[0][ch] = (s0 / c0) * sc + sh;
    desc[1][ch] = (s1 / c1) * sc + sh;

    const float lsf  = (float)Ls;
    const float mus  = ss / lsf;
    const float vars = sqk / lsf - mus * mus;
    const float rss  = rsqrtf(vars + 1e-5f);
    const float ssc  = rss * sgamma[ch];
    sscale[ch] = ssc;
    sshift[ch] = sbeta[ch] - mus * ssc;

    __syncthreads();
    if (ch < 16) {
        const int b = ch >> 3, h = ch & 7;
        float a = 0.f;
        for (int c = 0; c < COUT; ++c) a += desc[b][c] * fc1[c * 8 + h];
        hid[b][h] = fmaxf(a, 0.f);
    }
    __syncthreads();
    for (int b = 0; b < 2; ++b) {
        float a = 0.f;
        for (int h = 0; h < 8; ++h) a += hid[b][h] * fc2[h * COUT + ch];
        attn[b * COUT + ch] = 1.f / (1.f + expf(-a));
    }
}

// ---------------------------------------------------------------------------
// Epilogue: for sorted row s -> orig rid: out[rid] = relu(bn(raw)*attn + skip).
// ---------------------------------------------------------------------------
__global__ __launch_bounds__(256) void final_kernel(
    const __bf16* __restrict__ raw,
    const int* __restrict__ rowid,
    const int* __restrict__ boob,
    const int* __restrict__ ng_dev,
    float* __restrict__ out,
    const __bf16* __restrict__ G,
    const int* __restrict__ inv_skip,
    const float* __restrict__ scale, const float* __restrict__ shift,
    const float* __restrict__ sscale, const float* __restrict__ sshift,
    const float* __restrict__ attn)
{
    const int t  = threadIdx.x;
    const int c4 = (t & 31) * 4;
    const int rw = t >> 5;
    const float4 sc  = *(const float4*)&scale[c4];
    const float4 sh  = *(const float4*)&shift[c4];
    const float4 ssc = *(const float4*)&sscale[c4];
    const float4 ssh = *(const float4*)&sshift[c4];
    const float4 at0 = *(const float4*)&attn[c4];
    const float4 at1 = *(const float4*)&attn[COUT + c4];
    const int S = ng_dev[0] << 4;

    for (int s = blockIdx.x * 8 + rw; s < S; s += gridDim.x * 8) {
        const int rid = rowid[s];
        if (rid < 0) continue;
        const bf16x4 rv = *(const bf16x4*)&raw[(size_t)s * COUT + c4];
        const int b = boob[s];
        const int j = inv_skip[rid];
        const float4 av = b ? at1 : at0;
        float4 y;
        y.x = ((float)rv[0] * sc.x + sh.x) * av.x;
        y.y = ((float)rv[1] * sc.y + sh.y) * av.y;
        y.z = ((float)rv[2] * sc.z + sh.z) * av.z;
        y.w = ((float)rv[3] * sc.w + sh.w) * av.w;
        if (j >= 0) {
            const bf16x4 gg = *(const bf16x4*)&G[(size_t)j * COUT + c4];
            y.x += (float)gg[0] * ssc.x + ssh.x;
            y.y += (float)gg[1] * ssc.y + ssh.y;
            y.z += (float)gg[2] * ssc.z + ssh.z;
            y.w += (float)gg[3] * ssc.w + ssh.w;
        }
        y.x = y.x > 0.f ? y.x : 0.f;
        y.y = y.y > 0.f ? y.y : 0.f;
        y.z = y.z > 0.f ? y.z : 0.f;
        y.w = y.w > 0.f ? y.w : 0.f;
        *(float4*)&out[(size_t)rid * COUT + c4] = y;
    }
}

extern "C" void kernel_launch(void* const* d_in, const int* in_sizes, int n_in,
                              void* d_out, int out_size, void* d_ws, size_t ws_size,
                              hipStream_t stream)
{
    const float* feats  = (const float*)d_in[0];
    const float* Wc     = (const float*)d_in[1];
    const float* Wsk    = (const float*)d_in[2];
    const float* gamma  = (const float*)d_in[3];
    const float* beta   = (const float*)d_in[4];
    const float* sgamma = (const float*)d_in[5];
    const float* sbeta  = (const float*)d_in[6];
    const float* fc1    = (const float*)d_in[7];
    const float* fc2    = (const float*)d_in[8];
    const int* cin_idx  = (const int*)d_in[9];
    const int* cout_idx = (const int*)d_in[10];
    const int* sin_idx  = (const int*)d_in[11];
    const int* sout_idx = (const int*)d_in[12];
    const int* boo      = (const int*)d_in[13];

    const int N  = in_sizes[0] / CIN;
    const int P  = in_sizes[9] / 9;
    const int Ls = in_sizes[11];
    const int M  = in_sizes[13];
    const int maxS = ((M + 15) & ~15) + 512 * 16;   // upper bound on sorted rows
    const int maxG = maxS >> 4;
    const int rpb = (M + SB - 1) / SB;              // rows per sort block

    float* out = (float*)d_out;

    // workspace layout
    char* ws = (char*)d_ws;
    __bf16* fb = (__bf16*)ws;                       // (N+1) x CIN
    size_t off = (size_t)(N + 1) * CIN * sizeof(__bf16);
    off = (off + 255) & ~(size_t)255;
    __bf16* wfrag = (__bf16*)(ws + off);
    off += (size_t)160 * 64 * 8 * sizeof(__bf16);
    off = (off + 255) & ~(size_t)255;
    int* tap_in = (int*)(ws + off);                 // 9 x M (valid entries only)
    off += (size_t)9 * M * sizeof(int);
    off = (off + 255) & ~(size_t)255;
    __bf16* G = (__bf16*)(ws + off);                // Ls x COUT bf16
    off += (size_t)Ls * COUT * sizeof(__bf16);
    off = (off + 255) & ~(size_t)255;
    int* inv_skip = (int*)(ws + off);               // M
    off += (size_t)M * sizeof(int);
    off = (off + 255) & ~(size_t)255;
    int* pat_arr = (int*)(ws + off);                // M (bitmask)
    off += (size_t)M * sizeof(int);
    off = (off + 255) & ~(size_t)255;
    int* rowid = (int*)(ws + off);                  // maxS
    off += (size_t)maxS * sizeof(int);
    int* spat = (int*)(ws + off);                   // maxS
    off += (size_t)maxS * sizeof(int);
    int* boob = (int*)(ws + off);                   // maxS
    off += (size_t)maxS * sizeof(int);
    off = (off + 255) & ~(size_t)255;
    __bf16* raw = (__bf16*)(ws + off);              // maxS x 128 bf16
    off += (size_t)maxS * COUT * sizeof(__bf16);
    off = (off + 255) & ~(size_t)255;
    int* bh = (int*)(ws + off);                     // SB x 512 block hists/bases
    off += (size_t)SB * 512 * sizeof(int);
    int* ng_dev = (int*)(ws + off);
    off += 256;
    float* zstats = (float*)(ws + off);             // NC*384 + NSB*256
    off += (size_t)(NC * 384 + NSB * 256) * sizeof(float);
    int* msplit = (int*)(ws + off);
    off += 256;
    float* params = (float*)(ws + off);
    float* scale = params, *shift = params + 128;
    float* sscale = params + 256, *sshift = params + 384, *attn = params + 512;

    hipMemsetAsync(zstats, 0, (size_t)(NC * 384 + NSB * 256) * sizeof(float), stream);
    hipMemsetAsync(inv_skip, 0xFF, (size_t)M * sizeof(int), stream);      // -1
    hipMemsetAsync(pat_arr, 0, (size_t)M * sizeof(int), stream);

    // fused prep
    const int total8 = N * CIN / 8;
    const int nbA = (total8 + 255) / 256;
    const int nbB = (160 * 64 + 255) / 256;
    const int cpb = (P + 255) / 256;
    const int nbAB = nbA + nbB;
    const int nbABC = nbAB + 9 * cpb;
    const int nbABCD = nbABC + (Ls + 255) / 256;
    prep_kernel<<<nbABCD + 1, 256, 0, stream>>>(
        feats, fb, Wc, Wsk, wfrag, cin_idx, cout_idx, tap_in, pat_arr,
        sout_idx, inv_skip, boo, msplit,
        total8, P, cpb, Ls, N, M, nbA, nbAB, nbABC, nbABCD);

    // pattern sort (atomic-free, two-level)
    pat_kernel<<<SB, 256, 0, stream>>>(pat_arr, bh, M, rpb);
    scan_kernel<<<1, 512, 0, stream>>>(bh, rowid, ng_dev);
    scatter_kernel<<<SB, 256, 0, stream>>>(pat_arr, bh, rowid, spat, boob, boo, M, rpb);

    conv_mfma_kernel<<<SKB + (maxG + 3) / 4, 256, 0, stream>>>(
        fb, wfrag, tap_in, rowid, spat, boob, ng_dev, sin_idx,
        raw, G, zstats, N, M, Ls);

    params_kernel<<<1, 128, 0, stream>>>(
        zstats, msplit, gamma, beta, sgamma, sbeta, fc1, fc2,
        scale, shift, sscale, sshift, attn, Ls, M);

    final_kernel<<<2048, 256, 0, stream>>>(
        raw, rowid, boob, ng_dev, out, G, inv_skip,
        scale, shift, sscale, sshift, attn);
}